// Round 4
// baseline (383.937 us; speedup 1.0000x reference)
//
#include <hip/hip_runtime.h>
#include <cstdint>
#include <cstddef>

// Problem sizes (fixed by the reference)
constexpr int Bb = 64, Ss = 197, Dd = 1024, Hh = 4096;
constexpr int M  = Bb * Ss;            // 12608 tokens
constexpr int MT = (M + 255) / 256;    // 50 M-tiles (256-row tiles)
constexpr int Mpad = MT * 256;         // 12800 (padded rows)
constexpr int NBLK1 = (Hh / 256) * MT; // 800 GEMM1 blocks

// ws layout: slots u32[64] @0 | pmax_w f32[1024] @1024 | pmax_y f32[NBLK1] @8192 | data @32768
#define SL_S1    4
#define SL_BERF  5
#define SL_CERF  6
#define SL_SHIFT 7
#define SL_S2    8
#define SL_SA    9
#define SL_SOUT2 10
#define SL_SW1   11
#define SL_SW2   12

typedef int v4i __attribute__((ext_vector_type(4)));

#define GLD_LDS(g, l) \
  __builtin_amdgcn_global_load_lds((const __attribute__((address_space(1))) void*)(g), \
                                   (__attribute__((address_space(3))) void*)(l), 16, 0, 0)

// Pipeline barrier: inline-asm s_barrier with "memory" clobber (memory ops can't
// cross). Register-only MFMAs CAN sink past it (rule #18) — so every trailing
// barrier is preceded by sched_barrier(0) to pin them inside their phase.
#define PBAR() asm volatile("s_barrier" ::: "memory")
#define SCHED_FENCE() __builtin_amdgcn_sched_barrier(0)

__device__ __forceinline__ float blockmax256(float m) {
  #pragma unroll
  for (int off = 32; off; off >>= 1) m = fmaxf(m, __shfl_down(m, off, 64));
  __shared__ float wm[4];
  int lane = threadIdx.x & 63, wid = threadIdx.x >> 6;
  if (lane == 0) wm[wid] = m;
  __syncthreads();
  return fmaxf(fmaxf(wm[0], wm[1]), fmaxf(wm[2], wm[3]));
}

// blocks [0,512): w1 partial max; [512,1024): w2. Plain stores, no init needed.
__global__ void k_wmax(const float* __restrict__ w1, const float* __restrict__ w2,
                       int n4, float* __restrict__ pmax) {
  int b = blockIdx.x;
  const float4* s4 = (const float4*)(b < 512 ? w1 : w2);
  float m = 0.f;
  for (int i = (b & 511) * 256 + threadIdx.x; i < n4; i += 512 * 256) {
    float4 v = s4[i];
    m = fmaxf(m, fmaxf(fmaxf(fabsf(v.x), fabsf(v.y)), fmaxf(fabsf(v.z), fabsf(v.w))));
  }
  m = blockmax256(m);
  if (threadIdx.x == 0) pmax[b] = m;
}

// Reduce pmax_w -> s_w1/s_w2, then mirror the reference's f32 scalar math exactly.
__global__ void k_scalars1(unsigned* slu, const float* __restrict__ pmax,
                           const float* __restrict__ s_x_ptr) {
  int t = threadIdx.x;
  float m1 = fmaxf(pmax[t], pmax[t + 256]);
  float m2 = fmaxf(pmax[512 + t], pmax[768 + t]);
  __shared__ float r1[256], r2[256];
  r1[t] = m1; r2[t] = m2;
  __syncthreads();
  for (int s = 128; s; s >>= 1) {
    if (t < s) { r1[t] = fmaxf(r1[t], r1[t + s]); r2[t] = fmaxf(r2[t], r2[t + s]); }
    __syncthreads();
  }
  if (t == 0) {
    float* slf = (float*)slu;
    float s_w1 = r1[0] / 127.0f;
    float s_w2 = r2[0] / 127.0f;
    float s1  = s_x_ptr[0] * s_w1;                    // s_out of linear1
    float sfe = s1 / 1.4142f;                         // sf / K_SQRT2
    float berf = floorf(-1.769f / sfe);               // COEF_B / sf
    float cerf = floorf(((float)(1.0 / -0.2888)) / (sfe * sfe)); // COEF_C / sf^2
    float sig  = ((sfe * sfe) * -0.2888f) * 16384.0f; // sf^2*COEF_A * 2^14
    float shiftv = floorf(1.0f / sig);
    float s2 = (s1 * sig) / 2.0f;
    slf[SL_S1] = s1; slf[SL_BERF] = berf; slf[SL_CERF] = cerf;
    slf[SL_SHIFT] = shiftv; slf[SL_S2] = s2; slf[SL_SW1] = s_w1; slf[SL_SW2] = s_w2;
  }
}

// Reduce pmax_y (NBLK1 plain-stored block maxima) -> sa/sout2 + output scalar.
__global__ void k_scalars2(unsigned* slu, const float* __restrict__ pmax,
                           float* dout_scalar) {
  int t = threadIdx.x;
  float m = 0.f;
  for (int i = t; i < NBLK1; i += 256) m = fmaxf(m, pmax[i]);
  __shared__ float r1[256];
  r1[t] = m;
  __syncthreads();
  for (int s = 128; s; s >>= 1) {
    if (t < s) r1[t] = fmaxf(r1[t], r1[t + s]);
    __syncthreads();
  }
  if (t == 0) {
    float* slf = (float*)slu;
    float xm = fabsf(r1[0] * slf[SL_S2]);  // max |x_hat| (rounding monotone -> max commutes)
    float sa = xm / 127.0f;
    float sout2 = sa * slf[SL_SW2];
    slf[SL_SA] = sa; slf[SL_SOUT2] = sout2;
    *dout_scalar = sout2;                  // second reference output (scalar s)
  }
}

// Fused: quantize w1, w2 (float4 -> 4x int8) and convert/zero-pad x (int4 -> 4x int8).
__global__ void k_quantcvt(const float* __restrict__ w1, const float* __restrict__ w2,
                           const int* __restrict__ x, const unsigned* __restrict__ slu,
                           int8_t* __restrict__ w1q, int8_t* __restrict__ w2q,
                           int8_t* __restrict__ xq) {
  const float* slf = (const float*)slu;
  float sw1 = slf[SL_SW1], sw2 = slf[SL_SW2];
  const int n1 = Hh * Dd / 4, n2 = Dd * Hh / 4;
  const int nx = M * Dd / 4, n3 = Mpad * Dd / 4;
  const int total = n1 + n2 + n3;
  for (int i = blockIdx.x * blockDim.x + threadIdx.x; i < total; i += gridDim.x * blockDim.x) {
    if (i < n1 + n2) {
      bool first = i < n1;
      int idx = first ? i : i - n1;
      float sw = first ? sw1 : sw2;
      float4 v = ((const float4*)(first ? w1 : w2))[idx];
      int qa = (int)fminf(fmaxf(rintf(v.x / sw), -127.f), 127.f);
      int qb = (int)fminf(fmaxf(rintf(v.y / sw), -127.f), 127.f);
      int qc = (int)fminf(fmaxf(rintf(v.z / sw), -127.f), 127.f);
      int qd = (int)fminf(fmaxf(rintf(v.w / sw), -127.f), 127.f);
      unsigned p = (unsigned)(qa & 0xff) | ((unsigned)(qb & 0xff) << 8) |
                   ((unsigned)(qc & 0xff) << 16) | ((unsigned)(qd & 0xff) << 24);
      ((unsigned*)(first ? w1q : w2q))[idx] = p;
    } else {
      int idx = i - n1 - n2;
      unsigned p = 0u;
      if (idx < nx) {
        int4 v = ((const int4*)x)[idx];
        p = (unsigned)(v.x & 0xff) | ((unsigned)(v.y & 0xff) << 8) |
            ((unsigned)(v.z & 0xff) << 16) | ((unsigned)(v.w & 0xff) << 24);
      }
      ((unsigned*)xq)[idx] = p;
    }
  }
}

// ------------------------------------------------------------------------
// i8 GEMM, 256x256 tile, BK=128, 8 waves (2Mx4N), 4-phase pipelined K-loop.
//
// SAFETY INVARIANT (fix for the round-2 race): stages write ONLY the NEXT
// tile's buffer (buf nb); the buffer being read (buf cb) is NEVER written.
// A region's last ds_read and its overwrite are >= 6 barriers apart, and
// sched_barrier(0) before every trailing s_barrier pins MFMAs (and their
// lgkmcnt waits) inside their phase, so no instruction motion can close
// the window (rule #18: register-only MFMA may otherwise sink past an
// asm memory-clobber barrier).
//
// Stage schedule for tile kt (units of 16 KiB = 256 rows x 64 B k-half):
//   ph1: stage t(kt+1).UB0      ph2: stage t(kt+1).UA0, wait vmcnt(4)
//   ph3: stage t(kt+1).UB1      ph4: stage t(kt+1).UA1, wait vmcnt(4)
// ph2's wait lands t(kt).{UB1,UA1} (needed by ph3); ph4's wait lands
// t(kt+1).{UB0,UA0} (needed by next ph1). 4-8 loads stay in flight;
// vmcnt(0) only on the last tile. LDS 128 KiB = 2 x (A 32K + B 32K).
//
// LDS swizzle: 4 chunks/64B row; LDS slot (row,c) holds global chunk
// c ^ ((row>>1)&3). GLD_LDS dest stays lane-linear (t*16 / +8192); the
// swizzle is applied to the per-lane GLOBAL source; reads invert it
// (both-sides-or-neither rule, m104/m231).
//
// MFMA swapped mfma(bf,af): acc[i][j] reg r: m = wr*128+i*16+lm,
//                                            n = wc*64 +j*16+quad*4+r.
// MODE 0: GEMM1 + IntGELU -> block max|y| -> plain store pmax_y[bid]
// MODE 1: GEMM1 + IntGELU -> requant -> q int8, coalesced via LDS tile
// MODE 2: GEMM2 + bias     -> f32 out, float4 stores
// ------------------------------------------------------------------------
template <int K, int MODE>
__global__ __launch_bounds__(512, 2) void k_gemm(
    const int8_t* __restrict__ A, const int8_t* __restrict__ Bm,
    const float* __restrict__ bias, const unsigned* __restrict__ slu,
    int8_t* __restrict__ qout, float* __restrict__ fout, float* __restrict__ pmax_y,
    int Mreal, int Ncols) {
  constexpr int NK = K / 128;            // K-tiles (>= 8 here)
  __shared__ alignas(64) int8_t smem[131072];
  const int t = threadIdx.x;
  const int bm = blockIdx.y, bn = blockIdx.x;
  const int lane = t & 63, wid = t >> 6;
  const int wr = wid >> 2, wc = wid & 3;          // 2 x 4 wave grid
  const int lm = lane & 15, quad = lane >> 4;

  // staging geometry: thread t covers unit slots t and t+512
  const int srow = t >> 2;                         // 0..127 (then +128)
  const int scc  = (t & 3) ^ ((srow >> 1) & 3);    // pre-swizzled global chunk col
  const int8_t* aSrc = A  + (size_t)(bm * 256 + srow) * K + scc * 16;
  const int8_t* bSrc = Bm + (size_t)(bn * 256 + srow) * K + scc * 16;

  // ds_read byte offsets within a 16 KiB k-half unit (swizzled)
  int aoff[8], boff[4];
  #pragma unroll
  for (int i = 0; i < 8; i++) {
    int r = wr * 128 + i * 16 + lm;
    aoff[i] = r * 64 + ((quad ^ ((r >> 1) & 3)) << 4);
  }
  #pragma unroll
  for (int j = 0; j < 4; j++) {
    int r = wc * 64 + j * 16 + lm;
    boff[j] = r * 64 + ((quad ^ ((r >> 1) & 3)) << 4);
  }

  v4i acc[8][4] = {};

  auto stA = [&](int buf, int kt, int ks) {
    int8_t* d = smem + buf * 65536 + ks * 16384 + t * 16;
    const int8_t* s = aSrc + kt * 128 + ks * 64;
    GLD_LDS(s, d);
    GLD_LDS(s + (size_t)128 * K, d + 8192);
  };
  auto stB = [&](int buf, int kt, int ks) {
    int8_t* d = smem + buf * 65536 + 32768 + ks * 16384 + t * 16;
    const int8_t* s = bSrc + kt * 128 + ks * 64;
    GLD_LDS(s, d);
    GLD_LDS(s + (size_t)128 * K, d + 8192);
  };

  // Prologue: tile0's 4 units into buf0. vmcnt(4): UB0,UA0 landed (ph1's
  // data); UB1,UA1 stay in flight until kt=0 ph2's wait.
  stB(0, 0, 0); stA(0, 0, 0); stB(0, 0, 1); stA(0, 0, 1);
  asm volatile("s_waitcnt vmcnt(4)" ::: "memory");
  SCHED_FENCE();
  PBAR();

  #pragma unroll 1
  for (int kt = 0; kt < NK; ++kt) {
    const int cb = kt & 1, nb = cb ^ 1;
    const int8_t* Ac = smem + cb * 65536;
    const int8_t* Bc = Ac + 32768;
    const bool pf = (kt + 1 < NK);
    v4i bf[4], af[4];

    // ---- phase 1: ks0, m-half0 ---- stage t(kt+1).UB0 -> buf nb
    #pragma unroll
    for (int j = 0; j < 4; j++) bf[j] = *(const v4i*)(Bc + boff[j]);
    #pragma unroll
    for (int i = 0; i < 4; i++) af[i] = *(const v4i*)(Ac + aoff[i]);
    if (pf) stB(nb, kt + 1, 0);
    PBAR();
    __builtin_amdgcn_s_setprio(1);
    #pragma unroll
    for (int i = 0; i < 4; i++)
      #pragma unroll
      for (int j = 0; j < 4; j++)
        acc[i][j] = __builtin_amdgcn_mfma_i32_16x16x64_i8(bf[j], af[i], acc[i][j], 0, 0, 0);
    __builtin_amdgcn_s_setprio(0);
    SCHED_FENCE();
    PBAR();

    // ---- phase 2: ks0, m-half1 (bf reused) ---- stage t(kt+1).UA0; wait
    #pragma unroll
    for (int i = 0; i < 4; i++) af[i] = *(const v4i*)(Ac + aoff[4 + i]);
    if (pf) stA(nb, kt + 1, 0);
    PBAR();
    __builtin_amdgcn_s_setprio(1);
    #pragma unroll
    for (int i = 0; i < 4; i++)
      #pragma unroll
      for (int j = 0; j < 4; j++)
        acc[4 + i][j] = __builtin_amdgcn_mfma_i32_16x16x64_i8(bf[j], af[i], acc[4 + i][j], 0, 0, 0);
    __builtin_amdgcn_s_setprio(0);
    // lands t(kt).{UB1,UA1} (read by ph3/ph4); keeps t(kt+1).{UB0,UA0} in flight
    if (pf) asm volatile("s_waitcnt vmcnt(4)" ::: "memory");
    else    asm volatile("s_waitcnt vmcnt(0)" ::: "memory");
    SCHED_FENCE();
    PBAR();

    // ---- phase 3: ks1, m-half0 ---- stage t(kt+1).UB1
    #pragma unroll
    for (int j = 0; j < 4; j++) bf[j] = *(const v4i*)(Bc + 16384 + boff[j]);
    #pragma unroll
    for (int i = 0; i < 4; i++) af[i] = *(const v4i*)(Ac + 16384 + aoff[i]);
    if (pf) stB(nb, kt + 1, 1);
    PBAR();
    __builtin_amdgcn_s_setprio(1);
    #pragma unroll
    for (int i = 0; i < 4; i++)
      #pragma unroll
      for (int j = 0; j < 4; j++)
        acc[i][j] = __builtin_amdgcn_mfma_i32_16x16x64_i8(bf[j], af[i], acc[i][j], 0, 0, 0);
    __builtin_amdgcn_s_setprio(0);
    SCHED_FENCE();
    PBAR();

    // ---- phase 4: ks1, m-half1 ---- stage t(kt+1).UA1; wait
    #pragma unroll
    for (int i = 0; i < 4; i++) af[i] = *(const v4i*)(Ac + 16384 + aoff[4 + i]);
    if (pf) stA(nb, kt + 1, 1);
    PBAR();
    __builtin_amdgcn_s_setprio(1);
    #pragma unroll
    for (int i = 0; i < 4; i++)
      #pragma unroll
      for (int j = 0; j < 4; j++)
        acc[4 + i][j] = __builtin_amdgcn_mfma_i32_16x16x64_i8(bf[j], af[i], acc[4 + i][j], 0, 0, 0);
    __builtin_amdgcn_s_setprio(0);
    // lands t(kt+1).{UB0,UA0} (read by next ph1); keeps {UB1,UA1} in flight
    if (pf) asm volatile("s_waitcnt vmcnt(4)" ::: "memory");
    else    asm volatile("s_waitcnt vmcnt(0)" ::: "memory");
    SCHED_FENCE();
    PBAR();
  }

  const float* slf = (const float*)slu;
  if constexpr (MODE == 2) {
    float sout2 = slf[SL_SOUT2];
    float4 bq[4];                           // hoisted: quantized bias per j
    #pragma unroll
    for (int j = 0; j < 4; j++) {
      float4 bv = *(const float4*)(bias + bn * 256 + wc * 64 + j * 16 + quad * 4);
      bq[j].x = rintf(bv.x / sout2); bq[j].y = rintf(bv.y / sout2);
      bq[j].z = rintf(bv.z / sout2); bq[j].w = rintf(bv.w / sout2);
    }
    #pragma unroll
    for (int i = 0; i < 8; i++) {
      int gr = bm * 256 + wr * 128 + i * 16 + lm;
      if (gr < Mreal) {
        #pragma unroll
        for (int j = 0; j < 4; j++) {
          int gc0 = bn * 256 + wc * 64 + j * 16 + quad * 4;
          float4 o;
          o.x = (float)acc[i][j][0] + bq[j].x;
          o.y = (float)acc[i][j][1] + bq[j].y;
          o.z = (float)acc[i][j][2] + bq[j].z;
          o.w = (float)acc[i][j][3] + bq[j].w;
          *(float4*)(fout + (size_t)gr * Ncols + gc0) = o;
        }
      }
    }
  } else {
    float s1 = slf[SL_S1], berf = slf[SL_BERF], cerf = slf[SL_CERF], shiftv = slf[SL_SHIFT];
    float s2 = slf[SL_S2];
    float sa = (MODE == 1) ? slf[SL_SA] : 1.0f;
    float r_req = (MODE == 1) ? (s2 / sa) : 1.0f;
    float lmax = 0.f;
    float4 bq[4];                           // hoisted: rintf(bias/s1) per j
    #pragma unroll
    for (int j = 0; j < 4; j++) {
      float4 bv = *(const float4*)(bias + bn * 256 + wc * 64 + j * 16 + quad * 4);
      bq[j].x = rintf(bv.x / s1); bq[j].y = rintf(bv.y / s1);
      bq[j].z = rintf(bv.z / s1); bq[j].w = rintf(bv.w / s1);
    }
    #pragma unroll
    for (int i = 0; i < 8; i++) {
      int mrow = wr * 128 + i * 16 + lm;
      int gr = bm * 256 + mrow;
      bool rowok = gr < Mreal;
      #pragma unroll
      for (int j = 0; j < 4; j++) {
        int n0 = wc * 64 + j * 16 + quad * 4;
        unsigned packed = 0u;
        #pragma unroll
        for (int r = 0; r < 4; r++) {
          float a = (float)acc[i][j][r] + ((const float*)&bq[j])[r]; // exact (<2^24)
          float ax = fminf(fabsf(a), -berf);
          float tt = ax + berf;
          float u = tt * tt + cerf;          // always < 0 (proven in prior session)
          // sign trick: ref is sign(a)*u; at a==0 the value is annihilated by y=a*(..)
          float ye = (a < 0.f) ? -u : u;
          float yv = floorf(ye * (1.0f / 16384.0f));            // floor(y / 2^14), exact scale
          float y = a * (yv + shiftv);                          // y_int
          if constexpr (MODE == 0) {
            if (rowok) lmax = fmaxf(lmax, fabsf(y));
          } else {
            float qf = rintf(y * r_req);
            qf = fminf(fmaxf(qf, -128.f), 127.f);
            packed |= ((unsigned)((int)qf & 0xff)) << (8 * r);
          }
        }
        if constexpr (MODE == 1) {
          // LDS tile [256][272] (pad 16: keeps 16B alignment + de-banks rows)
          *(unsigned*)(smem + mrow * 272 + n0) = packed;
        }
      }
    }
    if constexpr (MODE == 0) {
      #pragma unroll
      for (int off = 32; off; off >>= 1) lmax = fmaxf(lmax, __shfl_down(lmax, off, 64));
      float* red = (float*)smem;
      if (lane == 0) red[wid] = lmax;       // pipeline's final PBAR precedes this
      __syncthreads();
      if (t == 0) {
        float b = fmaxf(fmaxf(fmaxf(red[0], red[1]), fmaxf(red[2], red[3])),
                        fmaxf(fmaxf(red[4], red[5]), fmaxf(red[6], red[7])));
        pmax_y[bm * gridDim.x + bn] = b;    // plain store — no atomics, no init
      }
    } else {
      __syncthreads();
      // coalesced store of the 256x256 int8 tile: 8 x 16B chunks per thread
      #pragma unroll
      for (int c2 = 0; c2 < 8; c2++) {
        int idx = c2 * 512 + t;
        int row = idx >> 4, c16 = (idx & 15) << 4;
        v4i v = *(const v4i*)(smem + row * 272 + c16);
        *(v4i*)(qout + (size_t)(bm * 256 + row) * Ncols + bn * 256 + c16) = v;
      }
    }
  }
}

extern "C" void kernel_launch(void* const* d_in, const int* in_sizes, int n_in,
                              void* d_out, int out_size, void* d_ws, size_t ws_size,
                              hipStream_t stream) {
  const int*   x   = (const int*)d_in[0];
  const float* s_x = (const float*)d_in[1];
  const float* w1  = (const float*)d_in[2];
  const float* b1  = (const float*)d_in[3];
  const float* w2  = (const float*)d_in[4];
  const float* b2  = (const float*)d_in[5];
  float* out = (float*)d_out;

  char* ws = (char*)d_ws;
  unsigned* slots = (unsigned*)ws;
  float* pmax_w = (float*)(ws + 1024);
  float* pmax_y = (float*)(ws + 8192);
  int8_t* w1q = (int8_t*)(ws + 32768);
  int8_t* w2q = w1q + (size_t)Hh * Dd;
  int8_t* xq  = w2q + (size_t)Dd * Hh;
  int8_t* qbuf = xq + (size_t)Mpad * Dd;   // total ws use ~74 MB

  k_wmax<<<1024, 256, 0, stream>>>(w1, w2, Hh * Dd / 4, pmax_w);
  k_scalars1<<<1, 256, 0, stream>>>(slots, pmax_w, s_x);
  k_quantcvt<<<1024, 256, 0, stream>>>(w1, w2, x, slots, w1q, w2q, xq);

  dim3 g1(Hh / 256, MT);   // 16 x 50
  // pass 0: GEMM1+GELU -> per-block max|y| (plain stores)
  k_gemm<Dd, 0><<<g1, 512, 0, stream>>>(xq, w1q, b1, slots, nullptr, nullptr,
                                        pmax_y, M, Hh);
  k_scalars2<<<1, 256, 0, stream>>>(slots, pmax_y, out + (size_t)M * Dd);
  // pass 1: GEMM1+GELU -> requant -> q (coalesced via LDS tile)
  k_gemm<Dd, 1><<<g1, 512, 0, stream>>>(xq, w1q, b1, slots, qbuf, nullptr,
                                        nullptr, M, Hh);
  dim3 g2(Dd / 256, MT);   // 4 x 50
  // GEMM2 + bias -> out (float4 stores)
  k_gemm<Hh, 2><<<g2, 512, 0, stream>>>(qbuf, w2q, b2, slots, nullptr, out,
                                        nullptr, M, Dd);
}

// Round 5
// 380.727 us; speedup vs baseline: 1.0084x; 1.0084x over previous
//
#include <hip/hip_runtime.h>
#include <cstdint>
#include <cstddef>

// Problem sizes (fixed by the reference)
constexpr int Bb = 64, Ss = 197, Dd = 1024, Hh = 4096;
constexpr int M  = Bb * Ss;            // 12608 tokens
constexpr int MT = (M + 255) / 256;    // 50 M-tiles (256-row tiles)
constexpr int Mpad = MT * 256;         // 12800 (padded rows)
constexpr int NBLK1 = (Hh / 256) * MT; // 800 GEMM1 blocks

// ws layout: slots u32[64] @0 | pmax_w f32[1024] @1024 | pmax_y f32[NBLK1] @8192 | data @32768
#define SL_S1    4
#define SL_BERF  5
#define SL_CERF  6
#define SL_SHIFT 7
#define SL_S2    8
#define SL_SA    9
#define SL_SOUT2 10
#define SL_SW1   11
#define SL_SW2   12

typedef int v4i __attribute__((ext_vector_type(4)));

#define GLD_LDS(g, l) \
  __builtin_amdgcn_global_load_lds((const __attribute__((address_space(1))) void*)(g), \
                                   (__attribute__((address_space(3))) void*)(l), 16, 0, 0)

// NON-DRAINING pipeline barrier (the round-4 fix): the builtin emits a bare
// s_barrier. An asm s_barrier with a "memory" clobber makes the backend drain
// vmcnt(0)/lgkmcnt(0) first, which silently killed the whole pipeline in r4
// (every counted vmcnt wait became a no-op; dur/MfmaUtil identical to the old
// drain structure). Counted waits below are bare volatile asm, NO clobber.
#define PBAR() __builtin_amdgcn_s_barrier()
#define SCHED_FENCE() __builtin_amdgcn_sched_barrier(0)
#define WAIT_VM(N) asm volatile("s_waitcnt vmcnt(" #N ")")

__device__ __forceinline__ float blockmax256(float m) {
  #pragma unroll
  for (int off = 32; off; off >>= 1) m = fmaxf(m, __shfl_down(m, off, 64));
  __shared__ float wm[4];
  int lane = threadIdx.x & 63, wid = threadIdx.x >> 6;
  if (lane == 0) wm[wid] = m;
  __syncthreads();
  return fmaxf(fmaxf(wm[0], wm[1]), fmaxf(wm[2], wm[3]));
}

// blocks [0,512): w1 partial max; [512,1024): w2. Plain stores, no init needed.
__global__ void k_wmax(const float* __restrict__ w1, const float* __restrict__ w2,
                       int n4, float* __restrict__ pmax) {
  int b = blockIdx.x;
  const float4* s4 = (const float4*)(b < 512 ? w1 : w2);
  float m = 0.f;
  for (int i = (b & 511) * 256 + threadIdx.x; i < n4; i += 512 * 256) {
    float4 v = s4[i];
    m = fmaxf(m, fmaxf(fmaxf(fabsf(v.x), fabsf(v.y)), fmaxf(fabsf(v.z), fabsf(v.w))));
  }
  m = blockmax256(m);
  if (threadIdx.x == 0) pmax[b] = m;
}

// Reduce pmax_w -> s_w1/s_w2, then mirror the reference's f32 scalar math exactly.
__global__ void k_scalars1(unsigned* slu, const float* __restrict__ pmax,
                           const float* __restrict__ s_x_ptr) {
  int t = threadIdx.x;
  float m1 = fmaxf(pmax[t], pmax[t + 256]);
  float m2 = fmaxf(pmax[512 + t], pmax[768 + t]);
  __shared__ float r1[256], r2[256];
  r1[t] = m1; r2[t] = m2;
  __syncthreads();
  for (int s = 128; s; s >>= 1) {
    if (t < s) { r1[t] = fmaxf(r1[t], r1[t + s]); r2[t] = fmaxf(r2[t], r2[t + s]); }
    __syncthreads();
  }
  if (t == 0) {
    float* slf = (float*)slu;
    float s_w1 = r1[0] / 127.0f;
    float s_w2 = r2[0] / 127.0f;
    float s1  = s_x_ptr[0] * s_w1;                    // s_out of linear1
    float sfe = s1 / 1.4142f;                         // sf / K_SQRT2
    float berf = floorf(-1.769f / sfe);               // COEF_B / sf
    float cerf = floorf(((float)(1.0 / -0.2888)) / (sfe * sfe)); // COEF_C / sf^2
    float sig  = ((sfe * sfe) * -0.2888f) * 16384.0f; // sf^2*COEF_A * 2^14
    float shiftv = floorf(1.0f / sig);
    float s2 = (s1 * sig) / 2.0f;
    slf[SL_S1] = s1; slf[SL_BERF] = berf; slf[SL_CERF] = cerf;
    slf[SL_SHIFT] = shiftv; slf[SL_S2] = s2; slf[SL_SW1] = s_w1; slf[SL_SW2] = s_w2;
  }
}

// Reduce pmax_y (NBLK1 plain-stored block maxima) -> sa/sout2 + output scalar.
__global__ void k_scalars2(unsigned* slu, const float* __restrict__ pmax,
                           float* dout_scalar) {
  int t = threadIdx.x;
  float m = 0.f;
  for (int i = t; i < NBLK1; i += 256) m = fmaxf(m, pmax[i]);
  __shared__ float r1[256];
  r1[t] = m;
  __syncthreads();
  for (int s = 128; s; s >>= 1) {
    if (t < s) r1[t] = fmaxf(r1[t], r1[t + s]);
    __syncthreads();
  }
  if (t == 0) {
    float* slf = (float*)slu;
    float xm = fabsf(r1[0] * slf[SL_S2]);  // max |x_hat| (rounding monotone -> max commutes)
    float sa = xm / 127.0f;
    float sout2 = sa * slf[SL_SW2];
    slf[SL_SA] = sa; slf[SL_SOUT2] = sout2;
    *dout_scalar = sout2;                  // second reference output (scalar s)
  }
}

// Fused: quantize w1, w2 (float4 -> 4x int8) and convert/zero-pad x (int4 -> 4x int8).
__global__ void k_quantcvt(const float* __restrict__ w1, const float* __restrict__ w2,
                           const int* __restrict__ x, const unsigned* __restrict__ slu,
                           int8_t* __restrict__ w1q, int8_t* __restrict__ w2q,
                           int8_t* __restrict__ xq) {
  const float* slf = (const float*)slu;
  float sw1 = slf[SL_SW1], sw2 = slf[SL_SW2];
  const int n1 = Hh * Dd / 4, n2 = Dd * Hh / 4;
  const int nx = M * Dd / 4, n3 = Mpad * Dd / 4;
  const int total = n1 + n2 + n3;
  for (int i = blockIdx.x * blockDim.x + threadIdx.x; i < total; i += gridDim.x * blockDim.x) {
    if (i < n1 + n2) {
      bool first = i < n1;
      int idx = first ? i : i - n1;
      float sw = first ? sw1 : sw2;
      float4 v = ((const float4*)(first ? w1 : w2))[idx];
      int qa = (int)fminf(fmaxf(rintf(v.x / sw), -127.f), 127.f);
      int qb = (int)fminf(fmaxf(rintf(v.y / sw), -127.f), 127.f);
      int qc = (int)fminf(fmaxf(rintf(v.z / sw), -127.f), 127.f);
      int qd = (int)fminf(fmaxf(rintf(v.w / sw), -127.f), 127.f);
      unsigned p = (unsigned)(qa & 0xff) | ((unsigned)(qb & 0xff) << 8) |
                   ((unsigned)(qc & 0xff) << 16) | ((unsigned)(qd & 0xff) << 24);
      ((unsigned*)(first ? w1q : w2q))[idx] = p;
    } else {
      int idx = i - n1 - n2;
      unsigned p = 0u;
      if (idx < nx) {
        int4 v = ((const int4*)x)[idx];
        p = (unsigned)(v.x & 0xff) | ((unsigned)(v.y & 0xff) << 8) |
            ((unsigned)(v.z & 0xff) << 16) | ((unsigned)(v.w & 0xff) << 24);
      }
      ((unsigned*)xq)[idx] = p;
    }
  }
}

// ------------------------------------------------------------------------
// i8 GEMM, 256x256 tile, BK=128, 8 waves (2Mx4N), 4-phase pipelined K-loop
// with NON-DRAINING barriers + counted vmcnt (T3+T4), setprio (T5).
//
// SAFETY: stages write ONLY the next tile's buffer (buf nb); the buffer
// being read is NEVER written. A region's last ds_read is >= 8 barriers
// before its overwrite. sched_barrier(0) after setprio(0) pins each MFMA
// cluster (and the compiler's lgkm waits) inside its phase, so every wave's
// LDS reads are complete before it passes the trailing barrier (this also
// protects the MODE-1 epilogue smem reuse). Wait ledger is monotone-safe:
// any compiler motion of loads across a counted wait only lengthens it.
//
// Stage schedule for tile kt (units of 16 KiB = 256 rows x 64 B k-half):
//   ph1: stage t(kt+1).UB0      ph2: stage t(kt+1).UA0, wait vmcnt(4)
//   ph3: stage t(kt+1).UB1      ph4: stage t(kt+1).UA1, wait vmcnt(4)
// ph2's wait lands t(kt).{UB1,UA1} (read by ph3/ph4); ph4's wait lands
// t(kt+1).{UB0,UA0} (read by next ph1). 4-8 loads always in flight;
// vmcnt(0) only on the last tile. LDS 128 KiB = 2 x (A 32K + B 32K).
//
// LDS swizzle: 4 chunks/64B row; LDS slot (row,c) holds global chunk
// c ^ ((row>>1)&3). GLD_LDS dest stays lane-linear; swizzle applied to the
// per-lane GLOBAL source; reads invert it (both-sides-or-neither).
//
// MFMA swapped mfma(bf,af): acc[i][j] reg r: m = wr*128+i*16+lm,
//                                            n = wc*64 +j*16+quad*4+r.
// MODE 0: GEMM1 + IntGELU -> block max|y| -> plain store pmax_y[bid]
// MODE 1: GEMM1 + IntGELU -> requant -> q int8, coalesced via LDS tile
// MODE 2: GEMM2 + bias     -> f32 out, float4 stores
// ------------------------------------------------------------------------
template <int K, int MODE>
__global__ __launch_bounds__(512, 2) void k_gemm(
    const int8_t* __restrict__ A, const int8_t* __restrict__ Bm,
    const float* __restrict__ bias, const unsigned* __restrict__ slu,
    int8_t* __restrict__ qout, float* __restrict__ fout, float* __restrict__ pmax_y,
    int Mreal, int Ncols) {
  constexpr int NK = K / 128;            // K-tiles (>= 8 here)
  __shared__ alignas(64) int8_t smem[131072];
  const int t = threadIdx.x;
  const int bm = blockIdx.y, bn = blockIdx.x;
  const int lane = t & 63, wid = t >> 6;
  const int wr = wid >> 2, wc = wid & 3;          // 2 x 4 wave grid
  const int lm = lane & 15, quad = lane >> 4;

  // staging geometry: thread t covers unit slots t and t+512
  const int srow = t >> 2;                         // 0..127 (then +128)
  const int scc  = (t & 3) ^ ((srow >> 1) & 3);    // pre-swizzled global chunk col
  const int8_t* aSrc = A  + (size_t)(bm * 256 + srow) * K + scc * 16;
  const int8_t* bSrc = Bm + (size_t)(bn * 256 + srow) * K + scc * 16;

  // ds_read byte offsets within a 16 KiB k-half unit (swizzled)
  int aoff[8], boff[4];
  #pragma unroll
  for (int i = 0; i < 8; i++) {
    int r = wr * 128 + i * 16 + lm;
    aoff[i] = r * 64 + ((quad ^ ((r >> 1) & 3)) << 4);
  }
  #pragma unroll
  for (int j = 0; j < 4; j++) {
    int r = wc * 64 + j * 16 + lm;
    boff[j] = r * 64 + ((quad ^ ((r >> 1) & 3)) << 4);
  }

  v4i acc[8][4] = {};

  auto stA = [&](int buf, int kt, int ks) {
    int8_t* d = smem + buf * 65536 + ks * 16384 + t * 16;
    const int8_t* s = aSrc + kt * 128 + ks * 64;
    GLD_LDS(s, d);
    GLD_LDS(s + (size_t)128 * K, d + 8192);
  };
  auto stB = [&](int buf, int kt, int ks) {
    int8_t* d = smem + buf * 65536 + 32768 + ks * 16384 + t * 16;
    const int8_t* s = bSrc + kt * 128 + ks * 64;
    GLD_LDS(s, d);
    GLD_LDS(s + (size_t)128 * K, d + 8192);
  };

  // Prologue: tile0's 4 units into buf0. vmcnt(4): UB0,UA0 landed (ph1's
  // data); UB1,UA1 stay in flight until kt=0 ph2's wait.
  stB(0, 0, 0); stA(0, 0, 0); stB(0, 0, 1); stA(0, 0, 1);
  WAIT_VM(4);
  SCHED_FENCE();
  PBAR();

  #pragma unroll 1
  for (int kt = 0; kt < NK; ++kt) {
    const int cb = kt & 1, nb = cb ^ 1;
    const int8_t* Ac = smem + cb * 65536;
    const int8_t* Bc = Ac + 32768;
    const bool pf = (kt + 1 < NK);
    v4i bf[4], af[4];

    // ---- phase 1: ks0, m-half0 ---- stage t(kt+1).UB0 -> buf nb
    #pragma unroll
    for (int j = 0; j < 4; j++) bf[j] = *(const v4i*)(Bc + boff[j]);
    #pragma unroll
    for (int i = 0; i < 4; i++) af[i] = *(const v4i*)(Ac + aoff[i]);
    if (pf) stB(nb, kt + 1, 0);
    PBAR();
    SCHED_FENCE();
    __builtin_amdgcn_s_setprio(1);
    #pragma unroll
    for (int i = 0; i < 4; i++)
      #pragma unroll
      for (int j = 0; j < 4; j++)
        acc[i][j] = __builtin_amdgcn_mfma_i32_16x16x64_i8(bf[j], af[i], acc[i][j], 0, 0, 0);
    __builtin_amdgcn_s_setprio(0);
    SCHED_FENCE();
    PBAR();

    // ---- phase 2: ks0, m-half1 (bf reused) ---- stage t(kt+1).UA0; wait
    #pragma unroll
    for (int i = 0; i < 4; i++) af[i] = *(const v4i*)(Ac + aoff[4 + i]);
    if (pf) stA(nb, kt + 1, 0);
    PBAR();
    SCHED_FENCE();
    __builtin_amdgcn_s_setprio(1);
    #pragma unroll
    for (int i = 0; i < 4; i++)
      #pragma unroll
      for (int j = 0; j < 4; j++)
        acc[4 + i][j] = __builtin_amdgcn_mfma_i32_16x16x64_i8(bf[j], af[i], acc[4 + i][j], 0, 0, 0);
    __builtin_amdgcn_s_setprio(0);
    SCHED_FENCE();
    // lands t(kt).{UB1,UA1} (read by ph3/ph4); keeps t(kt+1).{UB0,UA0} in flight
    if (pf) { WAIT_VM(4); } else { WAIT_VM(0); }
    SCHED_FENCE();
    PBAR();

    // ---- phase 3: ks1, m-half0 ---- stage t(kt+1).UB1
    #pragma unroll
    for (int j = 0; j < 4; j++) bf[j] = *(const v4i*)(Bc + 16384 + boff[j]);
    #pragma unroll
    for (int i = 0; i < 4; i++) af[i] = *(const v4i*)(Ac + 16384 + aoff[i]);
    if (pf) stB(nb, kt + 1, 1);
    PBAR();
    SCHED_FENCE();
    __builtin_amdgcn_s_setprio(1);
    #pragma unroll
    for (int i = 0; i < 4; i++)
      #pragma unroll
      for (int j = 0; j < 4; j++)
        acc[i][j] = __builtin_amdgcn_mfma_i32_16x16x64_i8(bf[j], af[i], acc[i][j], 0, 0, 0);
    __builtin_amdgcn_s_setprio(0);
    SCHED_FENCE();
    PBAR();

    // ---- phase 4: ks1, m-half1 ---- stage t(kt+1).UA1; wait
    #pragma unroll
    for (int i = 0; i < 4; i++) af[i] = *(const v4i*)(Ac + 16384 + aoff[4 + i]);
    if (pf) stA(nb, kt + 1, 1);
    PBAR();
    SCHED_FENCE();
    __builtin_amdgcn_s_setprio(1);
    #pragma unroll
    for (int i = 0; i < 4; i++)
      #pragma unroll
      for (int j = 0; j < 4; j++)
        acc[4 + i][j] = __builtin_amdgcn_mfma_i32_16x16x64_i8(bf[j], af[i], acc[4 + i][j], 0, 0, 0);
    __builtin_amdgcn_s_setprio(0);
    SCHED_FENCE();
    // lands t(kt+1).{UB0,UA0} (read by next ph1); keeps {UB1,UA1} in flight
    if (pf) { WAIT_VM(4); } else { WAIT_VM(0); }
    SCHED_FENCE();
    PBAR();
  }

  const float* slf = (const float*)slu;
  if constexpr (MODE == 2) {
    float sout2 = slf[SL_SOUT2];
    float4 bq[4];                           // hoisted: quantized bias per j
    #pragma unroll
    for (int j = 0; j < 4; j++) {
      float4 bv = *(const float4*)(bias + bn * 256 + wc * 64 + j * 16 + quad * 4);
      bq[j].x = rintf(bv.x / sout2); bq[j].y = rintf(bv.y / sout2);
      bq[j].z = rintf(bv.z / sout2); bq[j].w = rintf(bv.w / sout2);
    }
    #pragma unroll
    for (int i = 0; i < 8; i++) {
      int gr = bm * 256 + wr * 128 + i * 16 + lm;
      if (gr < Mreal) {
        #pragma unroll
        for (int j = 0; j < 4; j++) {
          int gc0 = bn * 256 + wc * 64 + j * 16 + quad * 4;
          float4 o;
          o.x = (float)acc[i][j][0] + bq[j].x;
          o.y = (float)acc[i][j][1] + bq[j].y;
          o.z = (float)acc[i][j][2] + bq[j].z;
          o.w = (float)acc[i][j][3] + bq[j].w;
          *(float4*)(fout + (size_t)gr * Ncols + gc0) = o;
        }
      }
    }
  } else {
    float s1 = slf[SL_S1], berf = slf[SL_BERF], cerf = slf[SL_CERF], shiftv = slf[SL_SHIFT];
    float s2 = slf[SL_S2];
    float sa = (MODE == 1) ? slf[SL_SA] : 1.0f;
    float r_req = (MODE == 1) ? (s2 / sa) : 1.0f;
    float lmax = 0.f;
    float4 bq[4];                           // hoisted: rintf(bias/s1) per j
    #pragma unroll
    for (int j = 0; j < 4; j++) {
      float4 bv = *(const float4*)(bias + bn * 256 + wc * 64 + j * 16 + quad * 4);
      bq[j].x = rintf(bv.x / s1); bq[j].y = rintf(bv.y / s1);
      bq[j].z = rintf(bv.z / s1); bq[j].w = rintf(bv.w / s1);
    }
    #pragma unroll
    for (int i = 0; i < 8; i++) {
      int mrow = wr * 128 + i * 16 + lm;
      int gr = bm * 256 + mrow;
      bool rowok = gr < Mreal;
      #pragma unroll
      for (int j = 0; j < 4; j++) {
        int n0 = wc * 64 + j * 16 + quad * 4;
        unsigned packed = 0u;
        #pragma unroll
        for (int r = 0; r < 4; r++) {
          float a = (float)acc[i][j][r] + ((const float*)&bq[j])[r]; // exact (<2^24)
          float ax = fminf(fabsf(a), -berf);
          float tt = ax + berf;
          float u = tt * tt + cerf;          // always < 0 (proven in prior session)
          // sign trick: ref is sign(a)*u; at a==0 the value is annihilated by y=a*(..)
          float ye = (a < 0.f) ? -u : u;
          float yv = floorf(ye * (1.0f / 16384.0f));            // floor(y / 2^14), exact scale
          float y = a * (yv + shiftv);                          // y_int
          if constexpr (MODE == 0) {
            if (rowok) lmax = fmaxf(lmax, fabsf(y));
          } else {
            float qf = rintf(y * r_req);
            qf = fminf(fmaxf(qf, -128.f), 127.f);
            packed |= ((unsigned)((int)qf & 0xff)) << (8 * r);
          }
        }
        if constexpr (MODE == 1) {
          // LDS tile [256][272] (pad 16: keeps 16B alignment + de-banks rows)
          *(unsigned*)(smem + mrow * 272 + n0) = packed;
        }
      }
    }
    if constexpr (MODE == 0) {
      #pragma unroll
      for (int off = 32; off; off >>= 1) lmax = fmaxf(lmax, __shfl_down(lmax, off, 64));
      float* red = (float*)smem;
      if (lane == 0) red[wid] = lmax;       // K-loop reads done (fenced) before final PBAR
      __syncthreads();
      if (t == 0) {
        float b = fmaxf(fmaxf(fmaxf(red[0], red[1]), fmaxf(red[2], red[3])),
                        fmaxf(fmaxf(red[4], red[5]), fmaxf(red[6], red[7])));
        pmax_y[bm * gridDim.x + bn] = b;    // plain store — no atomics, no init
      }
    } else {
      __syncthreads();
      // coalesced store of the 256x256 int8 tile: 8 x 16B chunks per thread
      #pragma unroll
      for (int c2 = 0; c2 < 8; c2++) {
        int idx = c2 * 512 + t;
        int row = idx >> 4, c16 = (idx & 15) << 4;
        v4i v = *(const v4i*)(smem + row * 272 + c16);
        *(v4i*)(qout + (size_t)(bm * 256 + row) * Ncols + bn * 256 + c16) = v;
      }
    }
  }
}

extern "C" void kernel_launch(void* const* d_in, const int* in_sizes, int n_in,
                              void* d_out, int out_size, void* d_ws, size_t ws_size,
                              hipStream_t stream) {
  const int*   x   = (const int*)d_in[0];
  const float* s_x = (const float*)d_in[1];
  const float* w1  = (const float*)d_in[2];
  const float* b1  = (const float*)d_in[3];
  const float* w2  = (const float*)d_in[4];
  const float* b2  = (const float*)d_in[5];
  float* out = (float*)d_out;

  char* ws = (char*)d_ws;
  unsigned* slots = (unsigned*)ws;
  float* pmax_w = (float*)(ws + 1024);
  float* pmax_y = (float*)(ws + 8192);
  int8_t* w1q = (int8_t*)(ws + 32768);
  int8_t* w2q = w1q + (size_t)Hh * Dd;
  int8_t* xq  = w2q + (size_t)Dd * Hh;
  int8_t* qbuf = xq + (size_t)Mpad * Dd;   // total ws use ~74 MB

  k_wmax<<<1024, 256, 0, stream>>>(w1, w2, Hh * Dd / 4, pmax_w);
  k_scalars1<<<1, 256, 0, stream>>>(slots, pmax_w, s_x);
  k_quantcvt<<<1024, 256, 0, stream>>>(w1, w2, x, slots, w1q, w2q, xq);

  dim3 g1(Hh / 256, MT);   // 16 x 50
  // pass 0: GEMM1+GELU -> per-block max|y| (plain stores)
  k_gemm<Dd, 0><<<g1, 512, 0, stream>>>(xq, w1q, b1, slots, nullptr, nullptr,
                                        pmax_y, M, Hh);
  k_scalars2<<<1, 256, 0, stream>>>(slots, pmax_y, out + (size_t)M * Dd);
  // pass 1: GEMM1+GELU -> requant -> q (coalesced via LDS tile)
  k_gemm<Dd, 1><<<g1, 512, 0, stream>>>(xq, w1q, b1, slots, qbuf, nullptr,
                                        nullptr, M, Hh);
  dim3 g2(Dd / 256, MT);   // 4 x 50
  // GEMM2 + bias -> out (float4 stores)
  k_gemm<Hh, 2><<<g2, 512, 0, stream>>>(qbuf, w2q, b2, slots, nullptr, out,
                                        nullptr, M, Dd);
}